// Round 4
// baseline (992.069 us; speedup 1.0000x reference)
//
#include <hip/hip_runtime.h>
#include <hip/hip_bf16.h>

#define NN   3072
#define NE   147456
#define NP   100000
#define HID  256
#define INCH 128
#define CATK 144
#define KPAD 160

typedef __attribute__((ext_vector_type(4))) float    f32x4;
typedef __attribute__((ext_vector_type(8))) _Float16 f16x8;
typedef __attribute__((ext_vector_type(4))) _Float16 f16x4;

// ---------------- async global->LDS (16B) ----------------
__device__ __forceinline__ void gload16(const void* g, void* l) {
  __builtin_amdgcn_global_load_lds((const __attribute__((address_space(1))) void*)g,
                                   (__attribute__((address_space(3))) void*)l, 16, 0, 0);
}

// ---------------- adjacency build + in-degree count ----------------
__global__ void edges_kernel(const int* __restrict__ ei, float* __restrict__ adj,
                             int* __restrict__ cnt) {
  int e = blockIdx.x * 256 + threadIdx.x;
  if (e < NE) {
    int s = ei[e], t = ei[NE + e];
    atomicAdd(&adj[(size_t)s * NN + t], 1.0f);
    atomicAdd(&cnt[t], 1);
  }
}

// row-normalize (fp16 out) + diag(rw) extract
__global__ void rownorm_kernel(const float* __restrict__ adj, _Float16* __restrict__ rw,
                               float* __restrict__ diag1) {
  int row = blockIdx.x, tid = threadIdx.x;
  const float* ap = adj + (size_t)row * NN;
  float s = 0.f;
  for (int j = tid; j < NN; j += 256) s += ap[j];
  for (int d = 32; d; d >>= 1) s += __shfl_xor(s, d);
  __shared__ float w4[4];
  if ((tid & 63) == 0) w4[tid >> 6] = s;
  __syncthreads();
  float inv = 1.f / fmaxf(w4[0] + w4[1] + w4[2] + w4[3], 1.f);
  _Float16* rp = rw + (size_t)row * NN;
  for (int j = tid; j < NN; j += 256) {
    float v = ap[j] * inv;
    rp[j] = (_Float16)v;
    if (j == row) diag1[row] = v;
  }
}

// ---------------- fp16 64x64-tiled transpose (rw -> rwT only) ----------------
__global__ void transpose_f16_kernel(const unsigned short* __restrict__ in,
                                     unsigned short* __restrict__ out) {
  __shared__ unsigned short t[64][65];
  int bx = blockIdx.x, by = blockIdx.y, tid = threadIdx.x;
#pragma unroll
  for (int ii = 0; ii < 16; ii++) {
    int lin = ii * 256 + tid, r = lin >> 6, c = lin & 63;
    t[r][c] = in[(size_t)(by * 64 + r) * NN + bx * 64 + c];
  }
  __syncthreads();
#pragma unroll
  for (int ii = 0; ii < 16; ii++) {
    int lin = ii * 256 + tid, r = lin >> 6, c = lin & 63;
    out[(size_t)(bx * 64 + r) * NN + by * 64 + c] = t[c][r];
  }
}

// ---------------- epilogue helper: diag(M*X) partial via LDS-staged X tile ----
// smem holds X[rowB0+j'][rowA0+i'] at smem[j'*136 + i'] (stride 136 for alignment/banks)
__device__ __forceinline__ void diag_prod_epi(const _Float16* __restrict__ X, float* __restrict__ dx,
                                              _Float16* smem, const f32x4 acc[4][4],
                                              int rowA0, int rowB0, int n,
                                              int tid, int lane, int wr, int wc) {
  __syncthreads();
#pragma unroll
  for (int s = 0; s < 8; s++) {
    int j2 = (tid >> 4) + s * 16;
    int cc = (tid & 15) * 8;
    *(f16x8*)(smem + j2 * 136 + cc) = *(const f16x8*)(X + (size_t)(rowB0 + j2) * n + rowA0 + cc);
  }
  __syncthreads();
  float dsum[4][4] = {};
#pragma unroll
  for (int i = 0; i < 4; i++)
#pragma unroll
    for (int j = 0; j < 4; j++) {
      int cl = wc * 64 + j * 16 + (lane & 15);
      int rl = wr * 64 + i * 16 + (lane >> 4) * 4;
      f16x4 xv = *(const f16x4*)(smem + cl * 136 + rl);
#pragma unroll
      for (int rr = 0; rr < 4; rr++) dsum[i][rr] += acc[i][j][rr] * (float)xv[rr];
    }
#pragma unroll
  for (int i = 0; i < 4; i++)
#pragma unroll
    for (int rr = 0; rr < 4; rr++) {
      float v = dsum[i][rr];
      v += __shfl_xor(v, 1); v += __shfl_xor(v, 2);
      v += __shfl_xor(v, 4); v += __shfl_xor(v, 8);
      if ((lane & 15) == 0)
        atomicAdd(dx + rowA0 + wr * 64 + i * 16 + (lane >> 4) * 4 + rr, v);
    }
}

// ---------------- fp16 MFMA GEMM: C = A * Bt^T, 128^2 tile BK=64, swizzled LDS ----
// Optional epilogue: CT dual-write, self-diag extract, up to 4 diag(M*X) products.
__global__ __launch_bounds__(256) void gemm_f16_nt(const _Float16* __restrict__ A,
                                                   const _Float16* __restrict__ Bt,
                                                   _Float16* __restrict__ C,
                                                   _Float16* __restrict__ CT,
                                                   float* __restrict__ dself,
                                                   const _Float16* __restrict__ X0,
                                                   const _Float16* __restrict__ X1,
                                                   const _Float16* __restrict__ X2,
                                                   const _Float16* __restrict__ X3,
                                                   float* __restrict__ d0, float* __restrict__ d1,
                                                   float* __restrict__ d2, float* __restrict__ d3,
                                                   int nX, int n) {
  __shared__ _Float16 smem[17408];   // loop: As[8192]+Bs[8192]; epilogue: X tile [128][136]
  _Float16* As = smem;
  _Float16* Bs = smem + 8192;
  const int nbx = n >> 7;
  const int nb = nbx * nbx;
  const int bid = blockIdx.x;
  const int cpx = nb >> 3;
  const int wg = (bid & 7) * cpx + (bid >> 3);
  const int by = wg / nbx, bx = wg % nbx;
  const int tid = threadIdx.x;
  const int lane = tid & 63, wave = tid >> 6;
  const int wr = wave >> 1, wc = wave & 1;
  const int rowA0 = by * 128, rowB0 = bx * 128;
  const int fr = lane & 15;
  const int rd = tid >> 3;
  const int cd = tid & 7;
  f32x4 acc[4][4] = {};
  const int nkt = n >> 6;
  for (int kt = 0; kt < nkt; ++kt) {
    const int k0 = kt << 6;
#pragma unroll
    for (int s = 0; s < 4; s++) {
      const int row = rd + s * 32;
      const int cg = (cd ^ (row & 7)) << 3;
      gload16(A + (size_t)(rowA0 + row) * n + k0 + cg, As + row * 64 + cd * 8);
      gload16(Bt + (size_t)(rowB0 + row) * n + k0 + cg, Bs + row * 64 + cd * 8);
    }
    __syncthreads();
#pragma unroll
    for (int ks = 0; ks < 2; ks++) {
      const int ch = ks * 4 + (lane >> 4);
      f16x8 af[4], bf[4];
#pragma unroll
      for (int i = 0; i < 4; i++) {
        const int Ra = wr * 64 + i * 16 + fr;
        const int Rb = wc * 64 + i * 16 + fr;
        af[i] = *(const f16x8*)(As + Ra * 64 + ((ch ^ (Ra & 7)) << 3));
        bf[i] = *(const f16x8*)(Bs + Rb * 64 + ((ch ^ (Rb & 7)) << 3));
      }
#pragma unroll
      for (int i = 0; i < 4; i++)
#pragma unroll
        for (int j = 0; j < 4; j++)
          acc[i][j] = __builtin_amdgcn_mfma_f32_16x16x32_f16(af[i], bf[j], acc[i][j], 0, 0, 0);
    }
    __syncthreads();
  }
  const int crow0 = rowA0 + wr * 64, ccol0 = rowB0 + wc * 64;
#pragma unroll
  for (int i = 0; i < 4; i++)
#pragma unroll
    for (int j = 0; j < 4; j++)
#pragma unroll
      for (int r = 0; r < 4; r++) {
        int row = crow0 + i * 16 + (lane >> 4) * 4 + r;
        int col = ccol0 + j * 16 + (lane & 15);
        C[(size_t)row * n + col] = (_Float16)acc[i][j][r];
      }
  if (CT) {
#pragma unroll
    for (int i = 0; i < 4; i++)
#pragma unroll
      for (int j = 0; j < 4; j++) {
        int cg = ccol0 + j * 16 + (lane & 15);
        int rg = crow0 + i * 16 + (lane >> 4) * 4;
        f16x4 t;
#pragma unroll
        for (int rr = 0; rr < 4; rr++) t[rr] = (_Float16)acc[i][j][rr];
        *(f16x4*)(CT + (size_t)cg * n + rg) = t;
      }
  }
  if (dself && rowA0 == rowB0 && wr == wc) {
    int g = lane >> 4, c = lane & 15;
    int rr = c - g * 4;
    if (rr >= 0 && rr < 4) {
#pragma unroll
      for (int i = 0; i < 4; i++)
        dself[crow0 + i * 16 + c] = acc[i][i][rr];
    }
  }
  if (nX > 0) diag_prod_epi(X0, d0, smem, acc, rowA0, rowB0, n, tid, lane, wr, wc);
  if (nX > 1) diag_prod_epi(X1, d1, smem, acc, rowA0, rowB0, n, tid, lane, wr, wc);
  if (nX > 2) diag_prod_epi(X2, d2, smem, acc, rowA0, rowB0, n, tid, lane, wr, wc);
  if (nX > 3) diag_prod_epi(X3, d3, smem, acc, rowA0, rowB0, n, tid, lane, wr, wc);
}

// ---------------- fp16 MFMA node GEMM: C[M][Nn] = A @ Bt^T + bias (+skip on hi cols) ----
__global__ __launch_bounds__(256) void gemm_f16_node(const _Float16* __restrict__ A,
                                                     const _Float16* __restrict__ Bt,
                                                     const float* __restrict__ bias,
                                                     const float* __restrict__ addhi,
                                                     float* __restrict__ C32,
                                                     _Float16* __restrict__ C16,
                                                     int M, int Nn, int K) {
  __shared__ _Float16 As[64 * 32];
  __shared__ _Float16 Bs[64 * 32];
  const int tid = threadIdx.x;
  const int lane = tid & 63, wave = tid >> 6;
  const int wr = wave >> 1, wc = wave & 1;
  const int m0 = blockIdx.y * 64, n0 = blockIdx.x * 64;
  const int fr = lane & 15, fk = (lane >> 4) * 8;
  const int gr = tid >> 2, gc = (tid & 3) * 8;
  f32x4 acc[2][2] = {};
  for (int k0 = 0; k0 < K; k0 += 32) {
    gload16(A + (size_t)(m0 + gr) * K + k0 + gc, As + tid * 8);
    gload16(Bt + (size_t)(n0 + gr) * K + k0 + gc, Bs + tid * 8);
    __syncthreads();
    f16x8 af[2], bf[2];
#pragma unroll
    for (int i = 0; i < 2; i++) {
      af[i] = *(const f16x8*)(As + (wr * 32 + i * 16 + fr) * 32 + fk);
      bf[i] = *(const f16x8*)(Bs + (wc * 32 + i * 16 + fr) * 32 + fk);
    }
#pragma unroll
    for (int i = 0; i < 2; i++)
#pragma unroll
      for (int j = 0; j < 2; j++)
        acc[i][j] = __builtin_amdgcn_mfma_f32_16x16x32_f16(af[i], bf[j], acc[i][j], 0, 0, 0);
    __syncthreads();
  }
  const int crow0 = m0 + wr * 32, ccol0 = n0 + wc * 32;
#pragma unroll
  for (int i = 0; i < 2; i++)
#pragma unroll
    for (int j = 0; j < 2; j++)
#pragma unroll
      for (int r = 0; r < 4; r++) {
        int row = crow0 + i * 16 + (lane >> 4) * 4 + r;
        int col = ccol0 + j * 16 + (lane & 15);
        float val = acc[i][j][r];
        if (bias) val += bias[col];
        if (addhi && col >= Nn - 256) val += addhi[(size_t)row * 256 + col - (Nn - 256)];
        if (C32) C32[(size_t)row * Nn + col] = val;
        if (C16) C16[(size_t)row * Nn + col] = (_Float16)val;
      }
}

// proj weight: [CATK][HID] f32 -> [HID][KPAD] f16
__global__ void wconv_proj_kernel(const float* __restrict__ W, _Float16* __restrict__ Wt) {
  int idx = blockIdx.x * 256 + threadIdx.x;
  if (idx >= HID * KPAD) return;
  int n = idx / KPAD, k = idx - n * KPAD;
  Wt[idx] = (k < CATK) ? (_Float16)W[(size_t)k * HID + n] : (_Float16)0.f;
}

// per-layer: Wq|Wk|Wv|Ws -> wt_cat [1024][256] f16; biases -> bcat[1024]
__global__ void wconv_cat_kernel(const float* __restrict__ Wq, const float* __restrict__ Wk,
                                 const float* __restrict__ Wv, const float* __restrict__ Wsk,
                                 const float* __restrict__ bq, const float* __restrict__ bk,
                                 const float* __restrict__ bv, const float* __restrict__ bsk,
                                 _Float16* __restrict__ wt, float* __restrict__ bcat) {
  int idx = blockIdx.x * 256 + threadIdx.x;
  if (idx < 1024) {
    int s = idx >> 8, j = idx & 255;
    bcat[idx] = (s == 0) ? bq[j] : (s == 1) ? bk[j] : (s == 2) ? bv[j] : bsk[j];
  }
  if (idx < 4 * HID * HID) {
    int nrow = idx >> 8, k = idx & 255;
    int s = nrow >> 8, nc = nrow & 255;
    const float* W = (s == 0) ? Wq : (s == 1) ? Wk : (s == 2) ? Wv : Wsk;
    wt[idx] = (_Float16)W[(size_t)k * HID + nc];
  }
}

// concat with inline PE: xc[i][c] = c<128 ? x : (c<144 ? pe(i,c-128) : 0)
__global__ void concat16_kernel(const float* __restrict__ x, const float* __restrict__ diags,
                                const float* __restrict__ w, const float* __restrict__ bb,
                                _Float16* __restrict__ xc) {
  int idx = blockIdx.x * 256 + threadIdx.x;
  if (idx >= NN * KPAD) return;
  int i = idx / KPAD, c = idx - i * KPAD;
  float v;
  if (c < INCH) v = x[(size_t)i * INCH + c];
  else if (c < CATK) {
    int d = c - INCH;
    v = bb[d];
#pragma unroll
    for (int t = 0; t < 16; t++) v += diags[t * NN + i] * w[t * 16 + d];
  } else v = 0.f;
  xc[idx] = (_Float16)v;
}

// ---------------- CSR ----------------
__global__ void csr_scan_kernel(const int* __restrict__ cnt, int* __restrict__ off) {
  int lane = threadIdx.x;  // single wave
  const int per = NN / 64;
  int s = 0;
  for (int i = 0; i < per; i++) s += cnt[lane * per + i];
  int run = s;
  for (int d = 1; d < 64; d <<= 1) {
    int t = __shfl_up(run, d);
    if (lane >= d) run += t;
  }
  int acc = run - s;
  for (int i = 0; i < per; i++) {
    off[lane * per + i] = acc;
    acc += cnt[lane * per + i];
  }
  if (lane == 63) off[NN] = acc;
}

__global__ void csr_fill_kernel(const int* __restrict__ sidx, const int* __restrict__ tidx,
                                const int* __restrict__ off, int* __restrict__ cur,
                                int* __restrict__ csrc) {
  int e = blockIdx.x * 256 + threadIdx.x;
  if (e >= NE) return;
  int t = tidx[e];
  int pos = atomicAdd(&cur[t], 1);
  csrc[off[t] + pos] = sidx[e];
}

// ---------------- fused attention + LayerNorm + ReLU: block per node ----------------
__global__ __launch_bounds__(256) void attn_ln_kernel(const int* __restrict__ off,
                                                      const int* __restrict__ csrc,
                                                      const _Float16* __restrict__ qkvz,
                                                      const float* __restrict__ g,
                                                      const float* __restrict__ b,
                                                      float* __restrict__ hb,
                                                      _Float16* __restrict__ h16) {
  int node = blockIdx.x, tid = threadIdx.x;
  int h = tid >> 6, lane = tid & 63;
  int beg = off[node], end = off[node + 1];
  float q = (float)qkvz[(size_t)node * 1024 + h * 64 + lane];
  float m = -INFINITY, denom = 0.f, acc = 0.f;
  for (int i = beg; i < end; ++i) {
    const _Float16* row = qkvz + (size_t)csrc[i] * 1024;
    float p = q * (float)row[256 + h * 64 + lane];
    for (int d = 32; d; d >>= 1) p += __shfl_xor(p, d);
    float sc = p * 0.125f;
    float mn = fmaxf(m, sc);
    float scale = expf(m - mn);
    float e = expf(sc - mn);
    denom = denom * scale + e;
    acc = acc * scale + e * (float)row[512 + h * 64 + lane];
    m = mn;
  }
  float agg = acc / fmaxf(denom, 1e-16f);
  float z = (float)qkvz[(size_t)node * 1024 + 768 + tid] + agg;
  // LayerNorm over 256
  float s = z;
  for (int d = 32; d; d >>= 1) s += __shfl_xor(s, d);
  __shared__ float w4[4], w4b[4];
  if (lane == 0) w4[h] = s;
  __syncthreads();
  float mu = (w4[0] + w4[1] + w4[2] + w4[3]) * (1.f / HID);
  float dv = z - mu;
  float qv = dv * dv;
  for (int d = 32; d; d >>= 1) qv += __shfl_xor(qv, d);
  if (lane == 0) w4b[h] = qv;
  __syncthreads();
  float var = (w4b[0] + w4b[1] + w4b[2] + w4b[3]) * (1.f / HID);
  float y = dv * (1.f / sqrtf(var + 1e-5f)) * g[tid] + b[tid];
  y = fmaxf(y, 0.f);
  hb[(size_t)node * HID + tid] = y;
  h16[(size_t)node * HID + tid] = (_Float16)y;
}

__global__ void decode_kernel(const float* __restrict__ h, const int* __restrict__ src,
                              const int* __restrict__ dst, float* __restrict__ out) {
  int wv = threadIdx.x >> 6, lane = threadIdx.x & 63;
  int p = blockIdx.x * 4 + wv;
  if (p >= NP) return;
  const float4* a = (const float4*)(h + (size_t)src[p] * HID);
  const float4* b = (const float4*)(h + (size_t)dst[p] * HID);
  float4 x = a[lane], y = b[lane];
  float s = x.x * y.x + x.y * y.y + x.z * y.z + x.w * y.w;
  for (int d = 32; d; d >>= 1) s += __shfl_xor(s, d);
  if (lane == 0) out[p] = 1.f / (1.f + expf(-s));
}

// ---------------- host launch ----------------
extern "C" void kernel_launch(void* const* d_in, const int* in_sizes, int n_in,
                              void* d_out, int out_size, void* d_ws, size_t ws_size,
                              hipStream_t stream) {
  const float* x      = (const float*)d_in[0];
  const int*   ei     = (const int*)d_in[1];
  const int*   src    = (const int*)d_in[2];
  const int*   dst    = (const int*)d_in[3];
  const float* rwse_w = (const float*)d_in[4];
  const float* rwse_b = (const float*)d_in[5];
  const float* proj_w = (const float*)d_in[6];
  const float* proj_b = (const float*)d_in[7];
  const float* Wq     = (const float*)d_in[8];
  const float* bq     = (const float*)d_in[9];
  const float* Wk     = (const float*)d_in[10];
  const float* bk     = (const float*)d_in[11];
  const float* Wv     = (const float*)d_in[12];
  const float* bv     = (const float*)d_in[13];
  const float* Wsk    = (const float*)d_in[14];
  const float* bs     = (const float*)d_in[15];
  const float* ln_g   = (const float*)d_in[16];
  const float* ln_b   = (const float*)d_in[17];
  float* out = (float*)d_out;

  const size_t MAT = (size_t)NN * NN * sizeof(_Float16);
  char* base = (char*)d_ws;
  _Float16* rw   = (_Float16*)(base + 0 * MAT);
  _Float16* rwT  = (_Float16*)(base + 1 * MAT);
  _Float16* rw2  = (_Float16*)(base + 2 * MAT);
  _Float16* rw3  = (_Float16*)(base + 3 * MAT);
  _Float16* rw4  = (_Float16*)(base + 4 * MAT);
  _Float16* rw4T = (_Float16*)(base + 5 * MAT);
  _Float16* rw8  = (_Float16*)(base + 6 * MAT);
  _Float16* rw12 = (_Float16*)(base + 7 * MAT);
  float* adj = (float*)(base + 6 * MAT);  // overlaps rw8/rw12: adj dead before they're written
  char* sm = base + 8 * MAT;
  // contiguous zeroed region: diags | cnt | cur
  float* diags = (float*)sm; sm += (size_t)16 * NN * 4;
  int* cnt = (int*)sm; sm += 12288;
  int* cur = (int*)sm; sm += 12288;
  const size_t ZERO_BYTES = (size_t)16 * NN * 4 + 12288 + 12288;
  int* off = (int*)sm; sm += 16384;
  int* csrc = (int*)sm; sm += (size_t)NE * 4;
  float* hbuf = (float*)sm; sm += (size_t)NN * HID * 4;
  _Float16* qkvz16 = (_Float16*)sm; sm += (size_t)NN * 1024 * 2;
  _Float16* h16  = (_Float16*)sm; sm += (size_t)NN * HID * 2;
  _Float16* xc16 = (_Float16*)sm; sm += (size_t)NN * KPAD * 2;
  _Float16* wt_proj = (_Float16*)sm; sm += (size_t)HID * KPAD * 2;
  _Float16* wt_cat[2]; float* bcat[2];
  for (int l = 0; l < 2; ++l) {
    wt_cat[l] = (_Float16*)sm; sm += (size_t)4 * HID * HID * 2;
    bcat[l]   = (float*)sm;    sm += 1024 * 4;
  }
  (void)in_sizes; (void)n_in; (void)out_size; (void)ws_size;

  const dim3 B256(256);
  const dim3 gT(NN / 64, NN / 64);
  const int  gG = (NN / 128) * (NN / 128);     // 576
  const dim3 gW(1024 / 64, NN / 64);           // wide qkv+skip GEMM
  const dim3 gS(HID / 64, NN / 64);            // proj GEMM

  // --- weight prep ---
  wconv_proj_kernel<<<(HID * KPAD + 255) / 256, B256, 0, stream>>>(proj_w, wt_proj);
  for (int l = 0; l < 2; ++l)
    wconv_cat_kernel<<<(4 * HID * HID + 255) / 256, B256, 0, stream>>>(
        Wq + (size_t)l * HID * HID, Wk + (size_t)l * HID * HID, Wv + (size_t)l * HID * HID,
        Wsk + (size_t)l * HID * HID, bq + l * HID, bk + l * HID, bv + l * HID, bs + l * HID,
        wt_cat[l], bcat[l]);

  // --- adjacency + in-degree + CSR ---
  hipMemsetAsync(adj, 0, (size_t)NN * NN * 4, stream);
  hipMemsetAsync(diags, 0, ZERO_BYTES, stream);
  edges_kernel<<<(NE + 255) / 256, B256, 0, stream>>>(ei, adj, cnt);
  rownorm_kernel<<<NN, B256, 0, stream>>>(adj, rw, diags);
  csr_scan_kernel<<<1, 64, 0, stream>>>(cnt, off);
  csr_fill_kernel<<<(NE + 255) / 256, B256, 0, stream>>>(ei, ei + NE, off, cur, csrc);

  // --- RWSE power chain with fused diag epilogues ---
  transpose_f16_kernel<<<gT, B256, 0, stream>>>((const unsigned short*)rw, (unsigned short*)rwT);
  // rw2 = rw*rw           ; extract diag(rw2)
  gemm_f16_nt<<<gG, B256, 0, stream>>>(rw, rwT, rw2, nullptr, diags + 1 * NN,
                                       nullptr, nullptr, nullptr, nullptr,
                                       nullptr, nullptr, nullptr, nullptr, 0, NN);
  // rw3 = rw2*rw          ; extract diag(rw3)
  gemm_f16_nt<<<gG, B256, 0, stream>>>(rw2, rwT, rw3, nullptr, diags + 2 * NN,
                                       nullptr, nullptr, nullptr, nullptr,
                                       nullptr, nullptr, nullptr, nullptr, 0, NN);
  // rw4 = rw3*rw          ; diag(rw4); rw4T; diag(rw4*rw{1,2,3}) -> t=5,6,7
  gemm_f16_nt<<<gG, B256, 0, stream>>>(rw3, rwT, rw4, rw4T, diags + 3 * NN,
                                       rw, rw2, rw3, nullptr,
                                       diags + 4 * NN, diags + 5 * NN, diags + 6 * NN, nullptr,
                                       3, NN);
  // rw8 = rw4*rw4         ; diag(rw8); diag(rw8*rw{1,2,3}) -> t=9,10,11
  gemm_f16_nt<<<gG, B256, 0, stream>>>(rw4, rw4T, rw8, nullptr, diags + 7 * NN,
                                       rw, rw2, rw3, nullptr,
                                       diags + 8 * NN, diags + 9 * NN, diags + 10 * NN, nullptr,
                                       3, NN);
  // rw12 = rw8*rw4        ; diag(rw12); diag(rw12*rw{1,2,3,4}) -> t=13,14,15,16
  gemm_f16_nt<<<gG, B256, 0, stream>>>(rw8, rw4T, rw12, nullptr, diags + 11 * NN,
                                       rw, rw2, rw3, rw4,
                                       diags + 12 * NN, diags + 13 * NN, diags + 14 * NN,
                                       diags + 15 * NN, 4, NN);

  // --- input projection (PE inline in concat) ---
  concat16_kernel<<<(NN * KPAD + 255) / 256, B256, 0, stream>>>(x, diags, rwse_w, rwse_b, xc16);
  gemm_f16_node<<<gS, B256, 0, stream>>>(xc16, wt_proj, proj_b, nullptr, hbuf, h16,
                                         NN, HID, KPAD);

  // --- transformer layers: [qkv|z] wide GEMM + fused attn/LN ---
  for (int l = 0; l < 2; ++l) {
    gemm_f16_node<<<gW, B256, 0, stream>>>(h16, wt_cat[l], bcat[l], hbuf, nullptr, qkvz16,
                                           NN, 1024, HID);
    attn_ln_kernel<<<NN, B256, 0, stream>>>(off, csrc, qkvz16, ln_g + l * HID, ln_b + l * HID,
                                            hbuf, h16);
  }

  decode_kernel<<<NP / 4, B256, 0, stream>>>(hbuf, src, dst, out);
}

// Round 5
// 792.402 us; speedup vs baseline: 1.2520x; 1.2520x over previous
//
#include <hip/hip_runtime.h>
#include <hip/hip_bf16.h>

#define NN   3072
#define NE   147456
#define NP   100000
#define HID  256
#define INCH 128
#define CATK 144
#define KPAD 160

typedef __attribute__((ext_vector_type(4))) float    f32x4;
typedef __attribute__((ext_vector_type(8))) _Float16 f16x8;

// ---------------- async global->LDS (16B) ----------------
__device__ __forceinline__ void gload16(const void* g, void* l) {
  __builtin_amdgcn_global_load_lds((const __attribute__((address_space(1))) void*)g,
                                   (__attribute__((address_space(3))) void*)l, 16, 0, 0);
}

// ---------------- adjacency build + in-degree count ----------------
__global__ void edges_kernel(const int* __restrict__ ei, float* __restrict__ adj,
                             int* __restrict__ cnt) {
  int e = blockIdx.x * 256 + threadIdx.x;
  if (e < NE) {
    int s = ei[e], t = ei[NE + e];
    atomicAdd(&adj[(size_t)s * NN + t], 1.0f);
    atomicAdd(&cnt[t], 1);
  }
}

// row-normalize (fp16 out) + diag(rw) extract
__global__ void rownorm_kernel(const float* __restrict__ adj, _Float16* __restrict__ rw,
                               float* __restrict__ diag1) {
  int row = blockIdx.x, tid = threadIdx.x;
  const float* ap = adj + (size_t)row * NN;
  float s = 0.f;
  for (int j = tid; j < NN; j += 256) s += ap[j];
  for (int d = 32; d; d >>= 1) s += __shfl_xor(s, d);
  __shared__ float w4[4];
  if ((tid & 63) == 0) w4[tid >> 6] = s;
  __syncthreads();
  float inv = 1.f / fmaxf(w4[0] + w4[1] + w4[2] + w4[3], 1.f);
  _Float16* rp = rw + (size_t)row * NN;
  for (int j = tid; j < NN; j += 256) {
    float v = ap[j] * inv;
    rp[j] = (_Float16)v;
    if (j == row) diag1[row] = v;
  }
}

// ---------------- fp16 64x64-tiled transpose, 2 pairs via blockIdx.z ----------------
__global__ void transpose2_f16_kernel(const unsigned short* __restrict__ in0,
                                      unsigned short* __restrict__ out0,
                                      const unsigned short* __restrict__ in1,
                                      unsigned short* __restrict__ out1) {
  const unsigned short* in = blockIdx.z ? in1 : in0;
  unsigned short* out = blockIdx.z ? out1 : out0;
  __shared__ unsigned short t[64][65];
  int bx = blockIdx.x, by = blockIdx.y, tid = threadIdx.x;
#pragma unroll
  for (int ii = 0; ii < 16; ii++) {
    int lin = ii * 256 + tid, r = lin >> 6, c = lin & 63;
    t[r][c] = in[(size_t)(by * 64 + r) * NN + bx * 64 + c];
  }
  __syncthreads();
#pragma unroll
  for (int ii = 0; ii < 16; ii++) {
    int lin = ii * 256 + tid, r = lin >> 6, c = lin & 63;
    out[(size_t)(bx * 64 + r) * NN + by * 64 + c] = t[c][r];
  }
}

// ---------------- fp16 MFMA GEMM: C = A * Bt^T  (row-major [n][n]) ----------------
// R3-proven: 128x128 tile, BK=64, 4 waves, both-sides XOR-swizzled LDS,
// XCD-chunked block swizzle. DO NOT add epilogue work here (R4 lesson:
// VGPR/LDS growth from fused epilogues cost +62us/dispatch on the hot loop).
__global__ __launch_bounds__(256) void gemm_f16_nt(const _Float16* __restrict__ A,
                                                   const _Float16* __restrict__ Bt,
                                                   _Float16* __restrict__ C, int n) {
  __shared__ _Float16 As[128 * 64];
  __shared__ _Float16 Bs[128 * 64];
  const int nbx = n >> 7;
  const int nb = nbx * nbx;
  const int bid = blockIdx.x;
  const int cpx = nb >> 3;
  const int wg = (bid & 7) * cpx + (bid >> 3);
  const int by = wg / nbx, bx = wg % nbx;
  const int tid = threadIdx.x;
  const int lane = tid & 63, wave = tid >> 6;
  const int wr = wave >> 1, wc = wave & 1;
  const int rowA0 = by * 128, rowB0 = bx * 128;
  const int fr = lane & 15;
  const int rd = tid >> 3;   // stage row base 0..31
  const int cd = tid & 7;    // stage chunk 0..7
  f32x4 acc[4][4] = {};
  const int nkt = n >> 6;
  for (int kt = 0; kt < nkt; ++kt) {
    const int k0 = kt << 6;
#pragma unroll
    for (int s = 0; s < 4; s++) {
      const int row = rd + s * 32;
      const int cg = (cd ^ (row & 7)) << 3;   // inverse-swizzled global chunk
      gload16(A + (size_t)(rowA0 + row) * n + k0 + cg, As + row * 64 + cd * 8);
      gload16(Bt + (size_t)(rowB0 + row) * n + k0 + cg, Bs + row * 64 + cd * 8);
    }
    __syncthreads();
#pragma unroll
    for (int ks = 0; ks < 2; ks++) {
      const int ch = ks * 4 + (lane >> 4);
      f16x8 af[4], bf[4];
#pragma unroll
      for (int i = 0; i < 4; i++) {
        const int Ra = wr * 64 + i * 16 + fr;
        const int Rb = wc * 64 + i * 16 + fr;
        af[i] = *(const f16x8*)(As + Ra * 64 + ((ch ^ (Ra & 7)) << 3));
        bf[i] = *(const f16x8*)(Bs + Rb * 64 + ((ch ^ (Rb & 7)) << 3));
      }
#pragma unroll
      for (int i = 0; i < 4; i++)
#pragma unroll
        for (int j = 0; j < 4; j++)
          acc[i][j] = __builtin_amdgcn_mfma_f32_16x16x32_f16(af[i], bf[j], acc[i][j], 0, 0, 0);
    }
    __syncthreads();
  }
  const int crow0 = rowA0 + wr * 64, ccol0 = rowB0 + wc * 64;
#pragma unroll
  for (int i = 0; i < 4; i++)
#pragma unroll
    for (int j = 0; j < 4; j++)
#pragma unroll
      for (int r = 0; r < 4; r++) {
        int row = crow0 + i * 16 + (lane >> 4) * 4 + r;
        int col = ccol0 + j * 16 + (lane & 15);
        C[(size_t)row * n + col] = (_Float16)acc[i][j][r];
      }
}

// ---------------- all diagonals t=2..16 in one streaming pass ----------------
// diag(A.B)_i = sum_j A[i,j]*B^T[i,j]; pairs:
// t2=(rw,rwT) t3=(rw2,rwT) t4=(rw2,rw2T) t5..8=(rw4,rw{1,2,3,4}T)
// t9..12=(rw8,...) t13..16=(rw12,...)
__global__ __launch_bounds__(256) void diag_all_kernel(
    const _Float16* __restrict__ rw, const _Float16* __restrict__ rw2,
    const _Float16* __restrict__ rw4, const _Float16* __restrict__ rw8,
    const _Float16* __restrict__ rw12, const _Float16* __restrict__ rwT,
    const _Float16* __restrict__ rw2T, const _Float16* __restrict__ rw3T,
    const _Float16* __restrict__ rw4T, float* __restrict__ diags) {
  int row = blockIdx.x, tid = threadIdx.x;
  size_t base = (size_t)row * NN;
  const f16x8* pl1  = (const f16x8*)(rw + base);
  const f16x8* pl2  = (const f16x8*)(rw2 + base);
  const f16x8* pl4  = (const f16x8*)(rw4 + base);
  const f16x8* pl8  = (const f16x8*)(rw8 + base);
  const f16x8* pl12 = (const f16x8*)(rw12 + base);
  const f16x8* pr1  = (const f16x8*)(rwT + base);
  const f16x8* pr2  = (const f16x8*)(rw2T + base);
  const f16x8* pr3  = (const f16x8*)(rw3T + base);
  const f16x8* pr4  = (const f16x8*)(rw4T + base);
  float s[15];
#pragma unroll
  for (int k = 0; k < 15; k++) s[k] = 0.f;
  for (int j = tid; j < NN / 8; j += 256) {
    f16x8 L1 = pl1[j], L2 = pl2[j], L4 = pl4[j], L8 = pl8[j], L12 = pl12[j];
    f16x8 R1 = pr1[j], R2 = pr2[j], R3 = pr3[j], R4 = pr4[j];
#pragma unroll
    for (int r = 0; r < 8; r++) {
      float a1 = (float)L1[r], a2 = (float)L2[r], a4 = (float)L4[r],
            a8 = (float)L8[r], a12 = (float)L12[r];
      float b1 = (float)R1[r], b2 = (float)R2[r], b3 = (float)R3[r], b4 = (float)R4[r];
      s[0]  += a1 * b1;  s[1]  += a2 * b1;  s[2]  += a2 * b2;
      s[3]  += a4 * b1;  s[4]  += a4 * b2;  s[5]  += a4 * b3;  s[6]  += a4 * b4;
      s[7]  += a8 * b1;  s[8]  += a8 * b2;  s[9]  += a8 * b3;  s[10] += a8 * b4;
      s[11] += a12 * b1; s[12] += a12 * b2; s[13] += a12 * b3; s[14] += a12 * b4;
    }
  }
  __shared__ float red[15][4];
  int wave = tid >> 6, lane = tid & 63;
#pragma unroll
  for (int k = 0; k < 15; k++) {
    float v = s[k];
    for (int d = 32; d; d >>= 1) v += __shfl_xor(v, d);
    if (lane == 0) red[k][wave] = v;
  }
  __syncthreads();
  if (tid < 15)
    diags[(size_t)(tid + 1) * NN + row] = red[tid][0] + red[tid][1] + red[tid][2] + red[tid][3];
}

// ---------------- fp16 MFMA node GEMM: C[M][Nn] = A @ Bt^T + bias (+skip on hi cols) ----
__global__ __launch_bounds__(256) void gemm_f16_node(const _Float16* __restrict__ A,
                                                     const _Float16* __restrict__ Bt,
                                                     const float* __restrict__ bias,
                                                     const float* __restrict__ addhi,
                                                     float* __restrict__ C32,
                                                     _Float16* __restrict__ C16,
                                                     int M, int Nn, int K) {
  __shared__ _Float16 As[64 * 32];
  __shared__ _Float16 Bs[64 * 32];
  const int tid = threadIdx.x;
  const int lane = tid & 63, wave = tid >> 6;
  const int wr = wave >> 1, wc = wave & 1;
  const int m0 = blockIdx.y * 64, n0 = blockIdx.x * 64;
  const int fr = lane & 15, fk = (lane >> 4) * 8;
  const int gr = tid >> 2, gc = (tid & 3) * 8;
  f32x4 acc[2][2] = {};
  for (int k0 = 0; k0 < K; k0 += 32) {
    gload16(A + (size_t)(m0 + gr) * K + k0 + gc, As + tid * 8);
    gload16(Bt + (size_t)(n0 + gr) * K + k0 + gc, Bs + tid * 8);
    __syncthreads();
    f16x8 af[2], bf[2];
#pragma unroll
    for (int i = 0; i < 2; i++) {
      af[i] = *(const f16x8*)(As + (wr * 32 + i * 16 + fr) * 32 + fk);
      bf[i] = *(const f16x8*)(Bs + (wc * 32 + i * 16 + fr) * 32 + fk);
    }
#pragma unroll
    for (int i = 0; i < 2; i++)
#pragma unroll
      for (int j = 0; j < 2; j++)
        acc[i][j] = __builtin_amdgcn_mfma_f32_16x16x32_f16(af[i], bf[j], acc[i][j], 0, 0, 0);
    __syncthreads();
  }
  const int crow0 = m0 + wr * 32, ccol0 = n0 + wc * 32;
#pragma unroll
  for (int i = 0; i < 2; i++)
#pragma unroll
    for (int j = 0; j < 2; j++)
#pragma unroll
      for (int r = 0; r < 4; r++) {
        int row = crow0 + i * 16 + (lane >> 4) * 4 + r;
        int col = ccol0 + j * 16 + (lane & 15);
        float val = acc[i][j][r];
        if (bias) val += bias[col];
        if (addhi && col >= Nn - 256) val += addhi[(size_t)row * 256 + col - (Nn - 256)];
        if (C32) C32[(size_t)row * Nn + col] = val;
        if (C16) C16[(size_t)row * Nn + col] = (_Float16)val;
      }
}

// proj weight: [CATK][HID] f32 -> [HID][KPAD] f16
__global__ void wconv_proj_kernel(const float* __restrict__ W, _Float16* __restrict__ Wt) {
  int idx = blockIdx.x * 256 + threadIdx.x;
  if (idx >= HID * KPAD) return;
  int n = idx / KPAD, k = idx - n * KPAD;
  Wt[idx] = (k < CATK) ? (_Float16)W[(size_t)k * HID + n] : (_Float16)0.f;
}

// per-layer: Wq|Wk|Wv|Ws -> wt_cat [1024][256] f16; biases -> bcat[1024]
__global__ void wconv_cat_kernel(const float* __restrict__ Wq, const float* __restrict__ Wk,
                                 const float* __restrict__ Wv, const float* __restrict__ Wsk,
                                 const float* __restrict__ bq, const float* __restrict__ bk,
                                 const float* __restrict__ bv, const float* __restrict__ bsk,
                                 _Float16* __restrict__ wt, float* __restrict__ bcat) {
  int idx = blockIdx.x * 256 + threadIdx.x;
  if (idx < 1024) {
    int s = idx >> 8, j = idx & 255;
    bcat[idx] = (s == 0) ? bq[j] : (s == 1) ? bk[j] : (s == 2) ? bv[j] : bsk[j];
  }
  if (idx < 4 * HID * HID) {
    int nrow = idx >> 8, k = idx & 255;
    int s = nrow >> 8, nc = nrow & 255;
    const float* W = (s == 0) ? Wq : (s == 1) ? Wk : (s == 2) ? Wv : Wsk;
    wt[idx] = (_Float16)W[(size_t)k * HID + nc];
  }
}

// concat with inline PE
__global__ void concat16_kernel(const float* __restrict__ x, const float* __restrict__ diags,
                                const float* __restrict__ w, const float* __restrict__ bb,
                                _Float16* __restrict__ xc) {
  int idx = blockIdx.x * 256 + threadIdx.x;
  if (idx >= NN * KPAD) return;
  int i = idx / KPAD, c = idx - i * KPAD;
  float v;
  if (c < INCH) v = x[(size_t)i * INCH + c];
  else if (c < CATK) {
    int d = c - INCH;
    v = bb[d];
#pragma unroll
    for (int t = 0; t < 16; t++) v += diags[t * NN + i] * w[t * 16 + d];
  } else v = 0.f;
  xc[idx] = (_Float16)v;
}

// ---------------- CSR ----------------
__global__ void csr_scan_kernel(const int* __restrict__ cnt, int* __restrict__ off) {
  int lane = threadIdx.x;  // single wave
  const int per = NN / 64;
  int s = 0;
  for (int i = 0; i < per; i++) s += cnt[lane * per + i];
  int run = s;
  for (int d = 1; d < 64; d <<= 1) {
    int t = __shfl_up(run, d);
    if (lane >= d) run += t;
  }
  int acc = run - s;
  for (int i = 0; i < per; i++) {
    off[lane * per + i] = acc;
    acc += cnt[lane * per + i];
  }
  if (lane == 63) off[NN] = acc;
}

__global__ void csr_fill_kernel(const int* __restrict__ sidx, const int* __restrict__ tidx,
                                const int* __restrict__ off, int* __restrict__ cur,
                                int* __restrict__ csrc) {
  int e = blockIdx.x * 256 + threadIdx.x;
  if (e >= NE) return;
  int t = tidx[e];
  int pos = atomicAdd(&cur[t], 1);
  csrc[off[t] + pos] = sidx[e];
}

// ---------------- fused attention + LayerNorm + ReLU: block per node ----------------
__global__ __launch_bounds__(256) void attn_ln_kernel(const int* __restrict__ off,
                                                      const int* __restrict__ csrc,
                                                      const _Float16* __restrict__ qkvz,
                                                      const float* __restrict__ g,
                                                      const float* __restrict__ b,
                                                      float* __restrict__ hb,
                                                      _Float16* __restrict__ h16) {
  int node = blockIdx.x, tid = threadIdx.x;
  int h = tid >> 6, lane = tid & 63;
  int beg = off[node], end = off[node + 1];
  float q = (float)qkvz[(size_t)node * 1024 + h * 64 + lane];
  float m = -INFINITY, denom = 0.f, acc = 0.f;
  for (int i = beg; i < end; ++i) {
    const _Float16* row = qkvz + (size_t)csrc[i] * 1024;
    float p = q * (float)row[256 + h * 64 + lane];
    for (int d = 32; d; d >>= 1) p += __shfl_xor(p, d);
    float sc = p * 0.125f;
    float mn = fmaxf(m, sc);
    float scale = expf(m - mn);
    float e = expf(sc - mn);
    denom = denom * scale + e;
    acc = acc * scale + e * (float)row[512 + h * 64 + lane];
    m = mn;
  }
  float agg = acc / fmaxf(denom, 1e-16f);
  float z = (float)qkvz[(size_t)node * 1024 + 768 + tid] + agg;
  // LayerNorm over 256
  float s = z;
  for (int d = 32; d; d >>= 1) s += __shfl_xor(s, d);
  __shared__ float w4[4], w4b[4];
  if (lane == 0) w4[h] = s;
  __syncthreads();
  float mu = (w4[0] + w4[1] + w4[2] + w4[3]) * (1.f / HID);
  float dv = z - mu;
  float qv = dv * dv;
  for (int d = 32; d; d >>= 1) qv += __shfl_xor(qv, d);
  if (lane == 0) w4b[h] = qv;
  __syncthreads();
  float var = (w4b[0] + w4b[1] + w4b[2] + w4b[3]) * (1.f / HID);
  float y = dv * (1.f / sqrtf(var + 1e-5f)) * g[tid] + b[tid];
  y = fmaxf(y, 0.f);
  hb[(size_t)node * HID + tid] = y;
  h16[(size_t)node * HID + tid] = (_Float16)y;
}

__global__ void decode_kernel(const float* __restrict__ h, const int* __restrict__ src,
                              const int* __restrict__ dst, float* __restrict__ out) {
  int wv = threadIdx.x >> 6, lane = threadIdx.x & 63;
  int p = blockIdx.x * 4 + wv;
  if (p >= NP) return;
  const float4* a = (const float4*)(h + (size_t)src[p] * HID);
  const float4* b = (const float4*)(h + (size_t)dst[p] * HID);
  float4 x = a[lane], y = b[lane];
  float s = x.x * y.x + x.y * y.y + x.z * y.z + x.w * y.w;
  for (int d = 32; d; d >>= 1) s += __shfl_xor(s, d);
  if (lane == 0) out[p] = 1.f / (1.f + expf(-s));
}

// ---------------- host launch ----------------
extern "C" void kernel_launch(void* const* d_in, const int* in_sizes, int n_in,
                              void* d_out, int out_size, void* d_ws, size_t ws_size,
                              hipStream_t stream) {
  const float* x      = (const float*)d_in[0];
  const int*   ei     = (const int*)d_in[1];
  const int*   src    = (const int*)d_in[2];
  const int*   dst    = (const int*)d_in[3];
  const float* rwse_w = (const float*)d_in[4];
  const float* rwse_b = (const float*)d_in[5];
  const float* proj_w = (const float*)d_in[6];
  const float* proj_b = (const float*)d_in[7];
  const float* Wq     = (const float*)d_in[8];
  const float* bq     = (const float*)d_in[9];
  const float* Wk     = (const float*)d_in[10];
  const float* bk     = (const float*)d_in[11];
  const float* Wv     = (const float*)d_in[12];
  const float* bv     = (const float*)d_in[13];
  const float* Wsk    = (const float*)d_in[14];
  const float* bs     = (const float*)d_in[15];
  const float* ln_g   = (const float*)d_in[16];
  const float* ln_b   = (const float*)d_in[17];
  float* out = (float*)d_out;

  const size_t MAT = (size_t)NN * NN * sizeof(_Float16);
  char* base = (char*)d_ws;
  _Float16* rw   = (_Float16*)(base + 0 * MAT);
  _Float16* rwT  = (_Float16*)(base + 1 * MAT);
  _Float16* rw2  = (_Float16*)(base + 2 * MAT);
  _Float16* rw3  = (_Float16*)(base + 3 * MAT);
  _Float16* rw4  = (_Float16*)(base + 4 * MAT);
  _Float16* rw4T = (_Float16*)(base + 5 * MAT);
  _Float16* rw8  = (_Float16*)(base + 6 * MAT);
  _Float16* rw12 = (_Float16*)(base + 7 * MAT);
  _Float16* rw2T = (_Float16*)(base + 8 * MAT);
  _Float16* rw3T = (_Float16*)(base + 9 * MAT);
  float* adj = (float*)(base + 8 * MAT);  // overlaps rw2T/rw3T: adj dead before those are written
  char* sm = base + 10 * MAT;
  float* diags = (float*)sm; sm += (size_t)16 * NN * 4;
  int* cnt = (int*)sm; sm += 12288;
  int* cur = (int*)sm; sm += 12288;
  int* off = (int*)sm; sm += 16384;
  int* csrc = (int*)sm; sm += (size_t)NE * 4;
  float* hbuf = (float*)sm; sm += (size_t)NN * HID * 4;
  _Float16* qkvz16 = (_Float16*)sm; sm += (size_t)NN * 1024 * 2;
  _Float16* h16  = (_Float16*)sm; sm += (size_t)NN * HID * 2;
  _Float16* xc16 = (_Float16*)sm; sm += (size_t)NN * KPAD * 2;
  _Float16* wt_proj = (_Float16*)sm; sm += (size_t)HID * KPAD * 2;
  _Float16* wt_cat[2]; float* bcat[2];
  for (int l = 0; l < 2; ++l) {
    wt_cat[l] = (_Float16*)sm; sm += (size_t)4 * HID * HID * 2;
    bcat[l]   = (float*)sm;    sm += 1024 * 4;
  }
  (void)in_sizes; (void)n_in; (void)out_size; (void)ws_size;

  const dim3 B256(256);
  const dim3 gT(NN / 64, NN / 64, 1);
  const dim3 gT2(NN / 64, NN / 64, 2);
  const int  gG = (NN / 128) * (NN / 128);     // 576
  const dim3 gW(1024 / 64, NN / 64);           // wide qkv+skip GEMM
  const dim3 gS(HID / 64, NN / 64);            // proj GEMM

  // --- weight prep ---
  wconv_proj_kernel<<<(HID * KPAD + 255) / 256, B256, 0, stream>>>(proj_w, wt_proj);
  for (int l = 0; l < 2; ++l)
    wconv_cat_kernel<<<(4 * HID * HID + 255) / 256, B256, 0, stream>>>(
        Wq + (size_t)l * HID * HID, Wk + (size_t)l * HID * HID, Wv + (size_t)l * HID * HID,
        Wsk + (size_t)l * HID * HID, bq + l * HID, bk + l * HID, bv + l * HID, bs + l * HID,
        wt_cat[l], bcat[l]);

  // --- adjacency + in-degree + CSR ---
  hipMemsetAsync(adj, 0, (size_t)NN * NN * 4, stream);
  hipMemsetAsync(cnt, 0, 24576, stream);   // cnt + cur contiguous
  edges_kernel<<<(NE + 255) / 256, B256, 0, stream>>>(ei, adj, cnt);
  rownorm_kernel<<<NN, B256, 0, stream>>>(adj, rw, diags);
  csr_scan_kernel<<<1, 64, 0, stream>>>(cnt, off);
  csr_fill_kernel<<<(NE + 255) / 256, B256, 0, stream>>>(ei, ei + NE, off, cur, csrc);

  // --- RWSE power chain (pristine GEMMs) ---
  transpose2_f16_kernel<<<gT, B256, 0, stream>>>((const unsigned short*)rw, (unsigned short*)rwT,
                                                 (const unsigned short*)rw, (unsigned short*)rwT);
  gemm_f16_nt<<<gG, B256, 0, stream>>>(rw, rwT, rw2, NN);    // rw2 = rw*rw
  gemm_f16_nt<<<gG, B256, 0, stream>>>(rw2, rwT, rw3, NN);   // rw3 = rw2*rw
  gemm_f16_nt<<<gG, B256, 0, stream>>>(rw3, rwT, rw4, NN);   // rw4 = rw3*rw
  transpose2_f16_kernel<<<gT, B256, 0, stream>>>((const unsigned short*)rw4, (unsigned short*)rw4T,
                                                 (const unsigned short*)rw4, (unsigned short*)rw4T);
  gemm_f16_nt<<<gG, B256, 0, stream>>>(rw4, rw4T, rw8, NN);  // rw8 = rw4*rw4
  gemm_f16_nt<<<gG, B256, 0, stream>>>(rw8, rw4T, rw12, NN); // rw12 = rw8*rw4
  transpose2_f16_kernel<<<gT2, B256, 0, stream>>>((const unsigned short*)rw2, (unsigned short*)rw2T,
                                                  (const unsigned short*)rw3, (unsigned short*)rw3T);
  // all 15 remaining diagonals in one streaming pass
  diag_all_kernel<<<NN, B256, 0, stream>>>(rw, rw2, rw4, rw8, rw12,
                                           rwT, rw2T, rw3T, rw4T, diags);

  // --- input projection (PE inline in concat) ---
  concat16_kernel<<<(NN * KPAD + 255) / 256, B256, 0, stream>>>(x, diags, rwse_w, rwse_b, xc16);
  gemm_f16_node<<<gS, B256, 0, stream>>>(xc16, wt_proj, proj_b, nullptr, hbuf, h16,
                                         NN, HID, KPAD);

  // --- transformer layers: [qkv|z] wide GEMM + fused attn/LN ---
  for (int l = 0; l < 2; ++l) {
    gemm_f16_node<<<gW, B256, 0, stream>>>(h16, wt_cat[l], bcat[l], hbuf, nullptr, qkvz16,
                                           NN, 1024, HID);
    attn_ln_kernel<<<NN, B256, 0, stream>>>(off, csrc, qkvz16, ln_g + l * HID, ln_b + l * HID,
                                            hbuf, h16);
  }

  decode_kernel<<<NP / 4, B256, 0, stream>>>(hbuf, src, dst, out);
}

// Round 6
// 713.923 us; speedup vs baseline: 1.3896x; 1.1099x over previous
//
#include <hip/hip_runtime.h>
#include <hip/hip_bf16.h>
#include <hip/hip_fp8.h>

#define NN   3072
#define NE   147456
#define NP   100000
#define HID  256
#define INCH 128
#define CATK 144
#define KPAD 160
#define FP8_S    1024.0f
#define FP8_IS   (1.0f / 1024.0f)
#define FP8_IS2  (1.0f / (1024.0f * 1024.0f))
#define MAXE 128

typedef __attribute__((ext_vector_type(4))) float    f32x4;
typedef __attribute__((ext_vector_type(8))) _Float16 f16x8;
typedef __attribute__((ext_vector_type(8))) unsigned char u8x8;

__device__ __forceinline__ float fp8f(unsigned char b) {
  __hip_fp8_e4m3 t; t.__x = b; return (float)t;
}
__device__ __forceinline__ unsigned char f2fp8(float v) {
  __hip_fp8_e4m3 t(v); return t.__x;
}

// ---------------- async global->LDS (16B) ----------------
__device__ __forceinline__ void gload16(const void* g, void* l) {
  __builtin_amdgcn_global_load_lds((const __attribute__((address_space(1))) void*)g,
                                   (__attribute__((address_space(3))) void*)l, 16, 0, 0);
}

// ---------------- adjacency build + in-degree count ----------------
__global__ void edges_kernel(const int* __restrict__ ei, float* __restrict__ adj,
                             int* __restrict__ cnt) {
  int e = blockIdx.x * 256 + threadIdx.x;
  if (e < NE) {
    int s = ei[e], t = ei[NE + e];
    atomicAdd(&adj[(size_t)s * NN + t], 1.0f);
    atomicAdd(&cnt[t], 1);
  }
}

// row-normalize -> fp8 (scaled by FP8_S) + diag(rw) extract (unscaled)
__global__ void rownorm_kernel(const float* __restrict__ adj, unsigned char* __restrict__ rw,
                               float* __restrict__ diag1) {
  int row = blockIdx.x, tid = threadIdx.x;
  const float* ap = adj + (size_t)row * NN;
  float s = 0.f;
  for (int j = tid; j < NN; j += 256) s += ap[j];
  for (int d = 32; d; d >>= 1) s += __shfl_xor(s, d);
  __shared__ float w4[4];
  if ((tid & 63) == 0) w4[tid >> 6] = s;
  __syncthreads();
  float inv = 1.f / fmaxf(w4[0] + w4[1] + w4[2] + w4[3], 1.f);
  unsigned char* rp = rw + (size_t)row * NN;
  for (int j = tid; j < NN; j += 256) {
    float v = ap[j] * inv;
    rp[j] = f2fp8(v * FP8_S);
    if (j == row) diag1[row] = v;
  }
}

// ---------------- u8 64x64-tiled transpose, up to 2 pairs via blockIdx.z ----------------
__global__ void transpose2_u8_kernel(const unsigned char* __restrict__ in0,
                                     unsigned char* __restrict__ out0,
                                     const unsigned char* __restrict__ in1,
                                     unsigned char* __restrict__ out1) {
  const unsigned char* in = blockIdx.z ? in1 : in0;
  unsigned char* out = blockIdx.z ? out1 : out0;
  __shared__ unsigned char t[64][68];
  int bx = blockIdx.x, by = blockIdx.y, tid = threadIdx.x;
#pragma unroll
  for (int ii = 0; ii < 4; ii++) {
    int lin = ii * 256 + tid;
    int r = lin >> 4, c4 = (lin & 15) * 4;
    unsigned int v = *(const unsigned int*)(in + (size_t)(by * 64 + r) * NN + bx * 64 + c4);
    t[r][c4] = v & 255; t[r][c4 + 1] = (v >> 8) & 255;
    t[r][c4 + 2] = (v >> 16) & 255; t[r][c4 + 3] = v >> 24;
  }
  __syncthreads();
#pragma unroll
  for (int ii = 0; ii < 4; ii++) {
    int lin = ii * 256 + tid;
    int r = lin >> 4, c4 = (lin & 15) * 4;
    unsigned int v = (unsigned int)t[c4][r] | ((unsigned int)t[c4 + 1][r] << 8) |
                     ((unsigned int)t[c4 + 2][r] << 16) | ((unsigned int)t[c4 + 3][r] << 24);
    *(unsigned int*)(out + (size_t)(bx * 64 + r) * NN + by * 64 + c4) = v;
  }
}

// ---------------- fp8 MFMA GEMM: C = A * Bt^T (all scaled by FP8_S) ----------------
// 128x128 tile, BK=64 (64 B/row), 4 waves, XOR-swizzled LDS (16B chunk ^= row&3),
// XCD-chunked block swizzle. Structure identical to the R3/R5-proven f16 kernel
// (R4 lesson: never graft epilogue work here). Epilogue rescales by 1/S -> fp8.
__global__ __launch_bounds__(256) void gemm_fp8_nt(const unsigned char* __restrict__ A,
                                                   const unsigned char* __restrict__ Bt,
                                                   unsigned char* __restrict__ C, int n) {
  __shared__ __align__(16) unsigned char As[128 * 64];
  __shared__ __align__(16) unsigned char Bs[128 * 64];
  const int nbx = n >> 7;
  const int nb = nbx * nbx;
  const int bid = blockIdx.x;
  const int cpx = nb >> 3;
  const int wg = (bid & 7) * cpx + (bid >> 3);
  const int by = wg / nbx, bx = wg % nbx;
  const int tid = threadIdx.x;
  const int lane = tid & 63, wave = tid >> 6;
  const int wr = wave >> 1, wc = wave & 1;
  const int rowA0 = by * 128, rowB0 = bx * 128;
  const int fr = lane & 15;
  const int kg = lane >> 4;       // k-group: byte offset kg*8 within K=32 slice
  const int sr = tid >> 2;        // stage row 0..63
  const int sc16 = tid & 3;       // stage 16B chunk 0..3
  f32x4 acc[4][4] = {};
  const int nkt = n >> 6;
  for (int kt = 0; kt < nkt; ++kt) {
    const int k0 = kt << 6;
#pragma unroll
    for (int s = 0; s < 2; s++) {
      const int row = sr + s * 64;
      const int cg = (sc16 ^ (row & 3)) << 4;   // inverse-swizzled global chunk
      gload16(A + (size_t)(rowA0 + row) * n + k0 + cg, As + row * 64 + sc16 * 16);
      gload16(Bt + (size_t)(rowB0 + row) * n + k0 + cg, Bs + row * 64 + sc16 * 16);
    }
    __syncthreads();
#pragma unroll
    for (int ks = 0; ks < 2; ks++) {
      const int kb = ks * 32 + kg * 8;
      const int kc = kb >> 4, kl = kb & 15;
      long af[4], bf[4];
#pragma unroll
      for (int i = 0; i < 4; i++) {
        const int Ra = wr * 64 + i * 16 + fr;
        const int Rb = wc * 64 + i * 16 + fr;
        af[i] = *(const long*)(As + Ra * 64 + ((kc ^ (Ra & 3)) << 4) + kl);
        bf[i] = *(const long*)(Bs + Rb * 64 + ((kc ^ (Rb & 3)) << 4) + kl);
      }
#pragma unroll
      for (int i = 0; i < 4; i++)
#pragma unroll
        for (int j = 0; j < 4; j++)
          acc[i][j] = __builtin_amdgcn_mfma_f32_16x16x32_fp8_fp8(af[i], bf[j], acc[i][j], 0, 0, 0);
    }
    __syncthreads();
  }
  const int crow0 = rowA0 + wr * 64, ccol0 = rowB0 + wc * 64;
#pragma unroll
  for (int i = 0; i < 4; i++)
#pragma unroll
    for (int j = 0; j < 4; j++)
#pragma unroll
      for (int r = 0; r < 4; r++) {
        int row = crow0 + i * 16 + (lane >> 4) * 4 + r;
        int col = ccol0 + j * 16 + (lane & 15);
        C[(size_t)row * n + col] = f2fp8(acc[i][j][r] * FP8_IS);
      }
}

// ---------------- all diagonals t=2..16 in one streaming pass (fp8 inputs) ----------
__global__ __launch_bounds__(256) void diag_all_kernel(
    const unsigned char* __restrict__ rw, const unsigned char* __restrict__ rw2,
    const unsigned char* __restrict__ rw4, const unsigned char* __restrict__ rw8,
    const unsigned char* __restrict__ rw12, const unsigned char* __restrict__ rwT,
    const unsigned char* __restrict__ rw2T, const unsigned char* __restrict__ rw3T,
    const unsigned char* __restrict__ rw4T, float* __restrict__ diags) {
  int row = blockIdx.x, tid = threadIdx.x;
  size_t base = (size_t)row * NN;
  const u8x8* pl1  = (const u8x8*)(rw + base);
  const u8x8* pl2  = (const u8x8*)(rw2 + base);
  const u8x8* pl4  = (const u8x8*)(rw4 + base);
  const u8x8* pl8  = (const u8x8*)(rw8 + base);
  const u8x8* pl12 = (const u8x8*)(rw12 + base);
  const u8x8* pr1  = (const u8x8*)(rwT + base);
  const u8x8* pr2  = (const u8x8*)(rw2T + base);
  const u8x8* pr3  = (const u8x8*)(rw3T + base);
  const u8x8* pr4  = (const u8x8*)(rw4T + base);
  float s[15];
#pragma unroll
  for (int k = 0; k < 15; k++) s[k] = 0.f;
  for (int j = tid; j < NN / 8; j += 256) {
    u8x8 L1 = pl1[j], L2 = pl2[j], L4 = pl4[j], L8 = pl8[j], L12 = pl12[j];
    u8x8 R1 = pr1[j], R2 = pr2[j], R3 = pr3[j], R4 = pr4[j];
#pragma unroll
    for (int r = 0; r < 8; r++) {
      float a1 = fp8f(L1[r]), a2 = fp8f(L2[r]), a4 = fp8f(L4[r]),
            a8 = fp8f(L8[r]), a12 = fp8f(L12[r]);
      float b1 = fp8f(R1[r]), b2 = fp8f(R2[r]), b3 = fp8f(R3[r]), b4 = fp8f(R4[r]);
      s[0]  += a1 * b1;  s[1]  += a2 * b1;  s[2]  += a2 * b2;
      s[3]  += a4 * b1;  s[4]  += a4 * b2;  s[5]  += a4 * b3;  s[6]  += a4 * b4;
      s[7]  += a8 * b1;  s[8]  += a8 * b2;  s[9]  += a8 * b3;  s[10] += a8 * b4;
      s[11] += a12 * b1; s[12] += a12 * b2; s[13] += a12 * b3; s[14] += a12 * b4;
    }
  }
  __shared__ float red[15][4];
  int wave = tid >> 6, lane = tid & 63;
#pragma unroll
  for (int k = 0; k < 15; k++) {
    float v = s[k];
    for (int d = 32; d; d >>= 1) v += __shfl_xor(v, d);
    if (lane == 0) red[k][wave] = v;
  }
  __syncthreads();
  if (tid < 15)
    diags[(size_t)(tid + 1) * NN + row] =
        (red[tid][0] + red[tid][1] + red[tid][2] + red[tid][3]) * FP8_IS2;
}

// ---------------- fp16 MFMA node GEMM: C[M][Nn] = A @ Bt^T + bias (+skip on hi cols) ----
__global__ __launch_bounds__(256) void gemm_f16_node(const _Float16* __restrict__ A,
                                                     const _Float16* __restrict__ Bt,
                                                     const float* __restrict__ bias,
                                                     const float* __restrict__ addhi,
                                                     float* __restrict__ C32,
                                                     _Float16* __restrict__ C16,
                                                     int M, int Nn, int K) {
  __shared__ _Float16 As[64 * 32];
  __shared__ _Float16 Bs[64 * 32];
  const int tid = threadIdx.x;
  const int lane = tid & 63, wave = tid >> 6;
  const int wr = wave >> 1, wc = wave & 1;
  const int m0 = blockIdx.y * 64, n0 = blockIdx.x * 64;
  const int fr = lane & 15, fk = (lane >> 4) * 8;
  const int gr = tid >> 2, gc = (tid & 3) * 8;
  f32x4 acc[2][2] = {};
  for (int k0 = 0; k0 < K; k0 += 32) {
    gload16(A + (size_t)(m0 + gr) * K + k0 + gc, As + tid * 8);
    gload16(Bt + (size_t)(n0 + gr) * K + k0 + gc, Bs + tid * 8);
    __syncthreads();
    f16x8 af[2], bf[2];
#pragma unroll
    for (int i = 0; i < 2; i++) {
      af[i] = *(const f16x8*)(As + (wr * 32 + i * 16 + fr) * 32 + fk);
      bf[i] = *(const f16x8*)(Bs + (wc * 32 + i * 16 + fr) * 32 + fk);
    }
#pragma unroll
    for (int i = 0; i < 2; i++)
#pragma unroll
      for (int j = 0; j < 2; j++)
        acc[i][j] = __builtin_amdgcn_mfma_f32_16x16x32_f16(af[i], bf[j], acc[i][j], 0, 0, 0);
    __syncthreads();
  }
  const int crow0 = m0 + wr * 32, ccol0 = n0 + wc * 32;
#pragma unroll
  for (int i = 0; i < 2; i++)
#pragma unroll
    for (int j = 0; j < 2; j++)
#pragma unroll
      for (int r = 0; r < 4; r++) {
        int row = crow0 + i * 16 + (lane >> 4) * 4 + r;
        int col = ccol0 + j * 16 + (lane & 15);
        float val = acc[i][j][r];
        if (bias) val += bias[col];
        if (addhi && col >= Nn - 256) val += addhi[(size_t)row * 256 + col - (Nn - 256)];
        if (C32) C32[(size_t)row * Nn + col] = val;
        if (C16) C16[(size_t)row * Nn + col] = (_Float16)val;
      }
}

// proj weight: [CATK][HID] f32 -> [HID][KPAD] f16
__global__ void wconv_proj_kernel(const float* __restrict__ W, _Float16* __restrict__ Wt) {
  int idx = blockIdx.x * 256 + threadIdx.x;
  if (idx >= HID * KPAD) return;
  int n = idx / KPAD, k = idx - n * KPAD;
  Wt[idx] = (k < CATK) ? (_Float16)W[(size_t)k * HID + n] : (_Float16)0.f;
}

// per-layer: Wq|Wk|Wv|Ws -> wt_cat [1024][256] f16; biases -> bcat[1024]
__global__ void wconv_cat_kernel(const float* __restrict__ Wq, const float* __restrict__ Wk,
                                 const float* __restrict__ Wv, const float* __restrict__ Wsk,
                                 const float* __restrict__ bq, const float* __restrict__ bk,
                                 const float* __restrict__ bv, const float* __restrict__ bsk,
                                 _Float16* __restrict__ wt, float* __restrict__ bcat) {
  int idx = blockIdx.x * 256 + threadIdx.x;
  if (idx < 1024) {
    int s = idx >> 8, j = idx & 255;
    bcat[idx] = (s == 0) ? bq[j] : (s == 1) ? bk[j] : (s == 2) ? bv[j] : bsk[j];
  }
  if (idx < 4 * HID * HID) {
    int nrow = idx >> 8, k = idx & 255;
    int s = nrow >> 8, nc = nrow & 255;
    const float* W = (s == 0) ? Wq : (s == 1) ? Wk : (s == 2) ? Wv : Wsk;
    wt[idx] = (_Float16)W[(size_t)k * HID + nc];
  }
}

// concat with inline PE
__global__ void concat16_kernel(const float* __restrict__ x, const float* __restrict__ diags,
                                const float* __restrict__ w, const float* __restrict__ bb,
                                _Float16* __restrict__ xc) {
  int idx = blockIdx.x * 256 + threadIdx.x;
  if (idx >= NN * KPAD) return;
  int i = idx / KPAD, c = idx - i * KPAD;
  float v;
  if (c < INCH) v = x[(size_t)i * INCH + c];
  else if (c < CATK) {
    int d = c - INCH;
    v = bb[d];
#pragma unroll
    for (int t = 0; t < 16; t++) v += diags[t * NN + i] * w[t * 16 + d];
  } else v = 0.f;
  xc[idx] = (_Float16)v;
}

// ---------------- CSR ----------------
__global__ void csr_scan_kernel(const int* __restrict__ cnt, int* __restrict__ off) {
  int lane = threadIdx.x;  // single wave
  const int per = NN / 64;
  int s = 0;
  for (int i = 0; i < per; i++) s += cnt[lane * per + i];
  int run = s;
  for (int d = 1; d < 64; d <<= 1) {
    int t = __shfl_up(run, d);
    if (lane >= d) run += t;
  }
  int acc = run - s;
  for (int i = 0; i < per; i++) {
    off[lane * per + i] = acc;
    acc += cnt[lane * per + i];
  }
  if (lane == 63) off[NN] = acc;
}

__global__ void csr_fill_kernel(const int* __restrict__ sidx, const int* __restrict__ tidx,
                                const int* __restrict__ off, int* __restrict__ cur,
                                int* __restrict__ csrc) {
  int e = blockIdx.x * 256 + threadIdx.x;
  if (e >= NE) return;
  int t = tidx[e];
  int pos = atomicAdd(&cur[t], 1);
  csrc[off[t] + pos] = sidx[e];
}

// ---------------- fused attention + LayerNorm + ReLU, two-phase ----------------
// Phase A: all (edge,head) scores thread-parallel into LDS.
// Phase B: wave(=head)-parallel max/denom, then ILP-friendly V accumulate.
__global__ __launch_bounds__(256) void attn_ln_kernel(const int* __restrict__ off,
                                                      const int* __restrict__ csrc,
                                                      const _Float16* __restrict__ qkvz,
                                                      const float* __restrict__ g,
                                                      const float* __restrict__ b,
                                                      float* __restrict__ hb,
                                                      _Float16* __restrict__ h16) {
  int node = blockIdx.x, tid = threadIdx.x;
  int h = tid >> 6, lane = tid & 63;
  int beg = off[node], end = off[node + 1];
  __shared__ _Float16 qs[256];
  __shared__ int srcs[MAXE];
  __shared__ float ps[4][MAXE];
  qs[tid] = qkvz[(size_t)node * 1024 + tid];
  float m_run = -INFINITY, d_run = 0.f, acc = 0.f;
  for (int chunk = beg; chunk < end; chunk += MAXE) {
    int ne = min(end - chunk, MAXE);
    if (tid < ne) srcs[tid] = csrc[chunk + tid];
    __syncthreads();
    // scores
    for (int p = tid; p < ne * 4; p += 256) {
      int e = p >> 2, h2 = p & 3;
      const f16x8* krow = (const f16x8*)(qkvz + (size_t)srcs[e] * 1024 + 256 + h2 * 64);
      const f16x8* qrow = (const f16x8*)(qs + h2 * 64);
      float sc = 0.f;
#pragma unroll
      for (int d8 = 0; d8 < 8; d8++) {
        f16x8 kv = krow[d8], qv = qrow[d8];
#pragma unroll
        for (int r = 0; r < 8; r++) sc += (float)qv[r] * (float)kv[r];
      }
      ps[h2][e] = sc * 0.125f;
    }
    __syncthreads();
    // per-head max
    float mloc = -INFINITY;
    for (int e = lane; e < ne; e += 64) mloc = fmaxf(mloc, ps[h][e]);
    for (int d = 32; d; d >>= 1) mloc = fmaxf(mloc, __shfl_xor(mloc, d));
    float mnew = fmaxf(m_run, mloc);
    // exp in place + denom
    float dloc = 0.f;
    for (int e = lane; e < ne; e += 64) {
      float p = __expf(ps[h][e] - mnew);
      ps[h][e] = p;
      dloc += p;
    }
    for (int d = 32; d; d >>= 1) dloc += __shfl_xor(dloc, d);
    float scale = __expf(m_run - mnew);   // exp(-inf)=0 on first chunk
    d_run = d_run * scale + dloc;
    acc *= scale;
    // V accumulate (iterations independent -> memory ILP)
    for (int e = 0; e < ne; e++) {
      acc += ps[h][e] * (float)qkvz[(size_t)srcs[e] * 1024 + 512 + h * 64 + lane];
    }
    m_run = mnew;
    __syncthreads();
  }
  float agg = acc / fmaxf(d_run, 1e-16f);
  float z = (float)qkvz[(size_t)node * 1024 + 768 + tid] + agg;
  // LayerNorm over 256
  float s = z;
  for (int d = 32; d; d >>= 1) s += __shfl_xor(s, d);
  __shared__ float w4[4], w4b[4];
  if (lane == 0) w4[h] = s;
  __syncthreads();
  float mu = (w4[0] + w4[1] + w4[2] + w4[3]) * (1.f / HID);
  float dv = z - mu;
  float qv = dv * dv;
  for (int d = 32; d; d >>= 1) qv += __shfl_xor(qv, d);
  if (lane == 0) w4b[h] = qv;
  __syncthreads();
  float var = (w4b[0] + w4b[1] + w4b[2] + w4b[3]) * (1.f / HID);
  float y = dv * (1.f / sqrtf(var + 1e-5f)) * g[tid] + b[tid];
  y = fmaxf(y, 0.f);
  hb[(size_t)node * HID + tid] = y;
  h16[(size_t)node * HID + tid] = (_Float16)y;
}

__global__ void decode_kernel(const float* __restrict__ h, const int* __restrict__ src,
                              const int* __restrict__ dst, float* __restrict__ out) {
  int wv = threadIdx.x >> 6, lane = threadIdx.x & 63;
  int p = blockIdx.x * 4 + wv;
  if (p >= NP) return;
  const float4* a = (const float4*)(h + (size_t)src[p] * HID);
  const float4* b = (const float4*)(h + (size_t)dst[p] * HID);
  float4 x = a[lane], y = b[lane];
  float s = x.x * y.x + x.y * y.y + x.z * y.z + x.w * y.w;
  for (int d = 32; d; d >>= 1) s += __shfl_xor(s, d);
  if (lane == 0) out[p] = 1.f / (1.f + expf(-s));
}

// ---------------- host launch ----------------
extern "C" void kernel_launch(void* const* d_in, const int* in_sizes, int n_in,
                              void* d_out, int out_size, void* d_ws, size_t ws_size,
                              hipStream_t stream) {
  const float* x      = (const float*)d_in[0];
  const int*   ei     = (const int*)d_in[1];
  const int*   src    = (const int*)d_in[2];
  const int*   dst    = (const int*)d_in[3];
  const float* rwse_w = (const float*)d_in[4];
  const float* rwse_b = (const float*)d_in[5];
  const float* proj_w = (const float*)d_in[6];
  const float* proj_b = (const float*)d_in[7];
  const float* Wq     = (const float*)d_in[8];
  const float* bq     = (const float*)d_in[9];
  const float* Wk     = (const float*)d_in[10];
  const float* bk     = (const float*)d_in[11];
  const float* Wv     = (const float*)d_in[12];
  const float* bv     = (const float*)d_in[13];
  const float* Wsk    = (const float*)d_in[14];
  const float* bs     = (const float*)d_in[15];
  const float* ln_g   = (const float*)d_in[16];
  const float* ln_b   = (const float*)d_in[17];
  float* out = (float*)d_out;

  const size_t M8 = (size_t)NN * NN;    // 9,437,184 bytes per fp8 matrix
  char* base = (char*)d_ws;
  unsigned char* rw   = (unsigned char*)(base + 0 * M8);
  unsigned char* rwT  = (unsigned char*)(base + 1 * M8);
  unsigned char* rw2  = (unsigned char*)(base + 2 * M8);
  unsigned char* rw3  = (unsigned char*)(base + 3 * M8);
  unsigned char* rw4  = (unsigned char*)(base + 4 * M8);
  unsigned char* rw4T = (unsigned char*)(base + 5 * M8);
  unsigned char* rw8  = (unsigned char*)(base + 6 * M8);
  unsigned char* rw12 = (unsigned char*)(base + 7 * M8);
  unsigned char* rw2T = (unsigned char*)(base + 8 * M8);
  unsigned char* rw3T = (unsigned char*)(base + 9 * M8);
  float* adj = (float*)(base + 6 * M8);  // f32 [NN][NN] = 4 fp8 slots (6..9); dead before rw8 written
  char* sm = base + 10 * M8;
  float* diags = (float*)sm; sm += (size_t)16 * NN * 4;
  int* cnt = (int*)sm; sm += 12288;
  int* cur = (int*)sm; sm += 12288;
  int* off = (int*)sm; sm += 16384;
  int* csrc = (int*)sm; sm += (size_t)NE * 4;
  float* hbuf = (float*)sm; sm += (size_t)NN * HID * 4;
  _Float16* qkvz16 = (_Float16*)sm; sm += (size_t)NN * 1024 * 2;
  _Float16* h16  = (_Float16*)sm; sm += (size_t)NN * HID * 2;
  _Float16* xc16 = (_Float16*)sm; sm += (size_t)NN * KPAD * 2;
  _Float16* wt_proj = (_Float16*)sm; sm += (size_t)HID * KPAD * 2;
  _Float16* wt_cat[2]; float* bcat[2];
  for (int l = 0; l < 2; ++l) {
    wt_cat[l] = (_Float16*)sm; sm += (size_t)4 * HID * HID * 2;
    bcat[l]   = (float*)sm;    sm += 1024 * 4;
  }
  (void)in_sizes; (void)n_in; (void)out_size; (void)ws_size;

  const dim3 B256(256);
  const dim3 gT1(NN / 64, NN / 64, 1);
  const dim3 gT2(NN / 64, NN / 64, 2);
  const int  gG = (NN / 128) * (NN / 128);     // 576
  const dim3 gW(1024 / 64, NN / 64);
  const dim3 gS(HID / 64, NN / 64);

  // --- weight prep ---
  wconv_proj_kernel<<<(HID * KPAD + 255) / 256, B256, 0, stream>>>(proj_w, wt_proj);
  for (int l = 0; l < 2; ++l)
    wconv_cat_kernel<<<(4 * HID * HID + 255) / 256, B256, 0, stream>>>(
        Wq + (size_t)l * HID * HID, Wk + (size_t)l * HID * HID, Wv + (size_t)l * HID * HID,
        Wsk + (size_t)l * HID * HID, bq + l * HID, bk + l * HID, bv + l * HID, bs + l * HID,
        wt_cat[l], bcat[l]);

  // --- adjacency + in-degree + CSR ---
  hipMemsetAsync(adj, 0, (size_t)NN * NN * 4, stream);
  hipMemsetAsync(cnt, 0, 24576, stream);   // cnt + cur contiguous
  edges_kernel<<<(NE + 255) / 256, B256, 0, stream>>>(ei, adj, cnt);
  rownorm_kernel<<<NN, B256, 0, stream>>>(adj, rw, diags);
  csr_scan_kernel<<<1, 64, 0, stream>>>(cnt, off);
  csr_fill_kernel<<<(NE + 255) / 256, B256, 0, stream>>>(ei, ei + NE, off, cur, csrc);

  // --- RWSE power chain (fp8, uniformly scaled by FP8_S) ---
  transpose2_u8_kernel<<<gT1, B256, 0, stream>>>(rw, rwT, rw, rwT);
  gemm_fp8_nt<<<gG, B256, 0, stream>>>(rw, rwT, rw2, NN);    // rw2 = rw*rw
  gemm_fp8_nt<<<gG, B256, 0, stream>>>(rw2, rwT, rw3, NN);   // rw3 = rw2*rw
  gemm_fp8_nt<<<gG, B256, 0, stream>>>(rw3, rwT, rw4, NN);   // rw4 = rw3*rw
  transpose2_u8_kernel<<<gT1, B256, 0, stream>>>(rw4, rw4T, rw4, rw4T);
  gemm_fp8_nt<<<gG, B256, 0, stream>>>(rw4, rw4T, rw8, NN);  // rw8 = rw4*rw4
  gemm_fp8_nt<<<gG, B256, 0, stream>>>(rw8, rw4T, rw12, NN); // rw12 = rw8*rw4
  transpose2_u8_kernel<<<gT2, B256, 0, stream>>>(rw2, rw2T, rw3, rw3T);
  diag_all_kernel<<<NN, B256, 0, stream>>>(rw, rw2, rw4, rw8, rw12,
                                           rwT, rw2T, rw3T, rw4T, diags);

  // --- input projection (PE inline in concat) ---
  concat16_kernel<<<(NN * KPAD + 255) / 256, B256, 0, stream>>>(x, diags, rwse_w, rwse_b, xc16);
  gemm_f16_node<<<gS, B256, 0, stream>>>(xc16, wt_proj, proj_b, nullptr, hbuf, h16,
                                         NN, HID, KPAD);

  // --- transformer layers ---
  for (int l = 0; l < 2; ++l) {
    gemm_f16_node<<<gW, B256, 0, stream>>>(h16, wt_cat[l], bcat[l], hbuf, nullptr, qkvz16,
                                           NN, 1024, HID);
    attn_ln_kernel<<<NN, B256, 0, stream>>>(off, csrc, qkvz16, ln_g + l * HID, ln_b + l * HID,
                                            hbuf, h16);
  }

  decode_kernel<<<NP / 4, B256, 0, stream>>>(hbuf, src, dst, out);
}